// Round 2
// baseline (346.579 us; speedup 1.0000x reference)
//
#include <hip/hip_runtime.h>

typedef __attribute__((ext_vector_type(8))) short bf16x8;
typedef __attribute__((ext_vector_type(4))) float f32x4;

static constexpr int HH = 224, WW = 224;
static constexpr int CIN = 64;
static constexpr int HW = HH * WW;   // 50176

__device__ __forceinline__ ushort f2bf(float f) {
    unsigned u = __builtin_bit_cast(unsigned, f);
    u += 0x7FFFu + ((u >> 16) & 1u);   // round-to-nearest-even
    return (ushort)(u >> 16);
}

// ws layout (ushort units):
//   w1r  [0, 36864)        9*64*64 bf16, [ch][n][c]
//   w2r  [36864, 40960)    64*64 bf16
//   zp   [40960, 41024)    128 B of zeros (halo zero-page)
//   xt   [41024, +8*HW*64) x as bf16, [b][p=y*W+x][c]  (51.4 MB)
__global__ void prep_kernel(const float* __restrict__ W1, const float* __restrict__ W2,
                            ushort* __restrict__ ws, int nfill) {
    const int idx = blockIdx.x * 256 + threadIdx.x;
    if (idx < 36864) {
        const int ch = idx >> 12;
        const int n = (idx >> 6) & 63;
        const int c = idx & 63;
        ws[idx] = f2bf(W1[n * 576 + c * 9 + ch]);
    } else if (idx < 40960) {
        ws[idx] = f2bf(W2[idx - 36864]);
    } else if (idx < nfill) {
        ws[idx] = 0;
    }
}

// Transpose + convert: x fp32 [b][c][y][x] -> xt bf16 [b][p][c].
// Each thread: 4 consecutive px x 8 channels. Reads 8x float4 (128B-coalesced
// per 8-lane group), writes 4x bf16x8 (full 128B px-lines covered per wave).
// 12 VMEM instrs per 192B of traffic (was 36 per thread in the scalar version).
__global__ __launch_bounds__(256)
void xprep_kernel(const float* __restrict__ xin, ushort* __restrict__ xt) {
    const int b = blockIdx.y;
    const float* xg = xin + (size_t)b * (CIN * HW);
    ushort* xo = xt + (size_t)b * ((size_t)HW * 64);
    const int idx = blockIdx.x * 256 + threadIdx.x;   // [0, 100352)
    const int cg = idx & 7;                           // 8-channel group
    const int p4 = idx >> 3;                          // px/4 index [0, 12544)
    const float* src = xg + (size_t)(cg * 8) * HW + p4 * 4;
    float4 v[8];
    #pragma unroll
    for (int j = 0; j < 8; ++j)
        v[j] = *reinterpret_cast<const float4*>(src + (size_t)j * HW);
    #pragma unroll
    for (int k = 0; k < 4; ++k) {
        bf16x8 o;
        #pragma unroll
        for (int j = 0; j < 8; ++j)
            o[j] = (short)f2bf(reinterpret_cast<const float*>(&v[j])[k]);
        *reinterpret_cast<bf16x8*>(xo + (size_t)(p4 * 4 + k) * 64 + cg * 8) = o;
    }
}

#define GLD_LDS16(g, l) __builtin_amdgcn_global_load_lds(                  \
    (const __attribute__((address_space(1))) void*)(g),                    \
    (__attribute__((address_space(3))) void*)(l), 16, 0, 0)

// 8 waves (512 threads) share one 51.2KB x-tile -> 3 blocks/CU = 24 waves/CU
// (6/SIMD, 2x the prior latency hiding). Each wave owns 1 row x 32 px.
// Staging = 6-7 global_load_lds per wave; LDS layout/swizzle unchanged:
// xs[p*64 + (c ^ ((p&7)*8))] via pre-swizzled per-lane global source.
__global__ __launch_bounds__(512, 6)
void mlpconv_fast(const ushort* __restrict__ xt, const ushort* __restrict__ w1r,
                  const float* __restrict__ b1, const ushort* __restrict__ w2r,
                  const float* __restrict__ b2, const ushort* __restrict__ zp,
                  float* __restrict__ out) {
    __shared__ ushort xs[10 * 40 * 64];   // 51,200 B

    const int tid = threadIdx.x;
    const int wave = tid >> 6;    // 0..7, owns output row y0+wave
    const int lane = tid & 63;
    const int l15 = lane & 15;
    const int quad = lane >> 4;

    const int x0 = blockIdx.x * 32;   // 7
    const int y0 = blockIdx.y * 8;    // 28
    const int b = blockIdx.z;         // 8

    const ushort* xtb = xt + (size_t)b * ((size_t)HW * 64);

    // Per-lane source swizzle (m173 pattern): lane l fills LDS slot
    // (px = l>>3, slot = l&7); slot s of px p holds channel-group s ^ (p&7).
    const int lpx = lane >> 3;
    const int laneoff = lpx * 64 + (((lane & 7) ^ lpx) * 8);   // ushort offset

    for (int q = wave; q < 50; q += 8) {     // 10 rows x 5 segments of 8 px
        const int r = q / 5;
        const int i = q - 5 * r;
        const int gy = y0 + r - 1;
        const int gx0 = x0 - 4 + i * 8;
        const ushort* real = xtb + (long)(gy * WW + gx0) * 64 + laneoff;
        const bool ok = ((unsigned)gy < (unsigned)HH) &
                        ((unsigned)(gx0 + lpx) < (unsigned)WW);
        const ushort* src = ok ? real : zp;   // halo lanes read the zero page
        GLD_LDS16(src, &xs[(r * 40 + i * 8) * 64]);
    }

    float b1v[4];
    #pragma unroll
    for (int nt = 0; nt < 4; ++nt) b1v[nt] = b1[nt * 16 + l15];

    f32x4 acc[2][4];   // C layout: col=lane&15 (=n), row=quad*4+reg (=px)
    #pragma unroll
    for (int mt = 0; mt < 2; ++mt)
        #pragma unroll
        for (int nt = 0; nt < 4; ++nt)
            acc[mt][nt] = (f32x4){b1v[nt], b1v[nt], b1v[nt], b1v[nt]};

    asm volatile("s_waitcnt vmcnt(0)" ::: "memory");
    __syncthreads();

    // ---- main loop: 18 k-steps (9 taps x 2 halves of 32 ch), barrier-free
    #pragma unroll 2
    for (int ks = 0; ks < 18; ++ks) {
        const int ch = ks >> 1;
        const int s = ks & 1;
        const int dy = ch / 3, dx = ch - 3 * (ch / 3);
        const int ko = s * 32 + quad * 8;
        bf16x8 bfr[4];
        #pragma unroll
        for (int nt = 0; nt < 4; ++nt)
            bfr[nt] = *reinterpret_cast<const bf16x8*>(
                w1r + ch * 4096 + (nt * 16 + l15) * 64 + ko);
        const int kswz = ko ^ (((l15 + dx + 3) & 7) * 8);
        const int row = wave + dy;
        #pragma unroll
        for (int mt = 0; mt < 2; ++mt) {
            const int col = mt * 16 + l15 + dx + 3;
            const bf16x8 afr = *reinterpret_cast<const bf16x8*>(
                &xs[(row * 40 + col) * 64 + kswz]);
            #pragma unroll
            for (int nt = 0; nt < 4; ++nt)
                acc[mt][nt] = __builtin_amdgcn_mfma_f32_16x16x32_bf16(
                    afr, bfr[nt], acc[mt][nt], 0, 0, 0);
        }
    }

    __syncthreads();   // other waves may still read xs; about to overwrite as h-scratch

    // ---- epilogue: ReLU -> bf16 h (per-wave LDS, no barrier) -> GEMM2 -> +b2 -> store
    float4 b2q[4];
    #pragma unroll
    for (int it = 0; it < 4; ++it)
        b2q[it] = *reinterpret_cast<const float4*>(b2 + it * 16 + quad * 4);

    bf16x8 wa2[2][4];   // W2 A-fragments, mt-invariant
    #pragma unroll
    for (int k2 = 0; k2 < 2; ++k2)
        #pragma unroll
        for (int it = 0; it < 4; ++it)
            wa2[k2][it] = *reinterpret_cast<const bf16x8*>(
                w2r + (it * 16 + l15) * 64 + k2 * 32 + quad * 8);

    ushort* myh = &xs[wave * (16 * 72)];   // 8 waves x 2304B = 18.4KB < 51.2KB
    float* outg = out + (size_t)b * (64 * HH * WW);
    const int gy = y0 + wave;

    #pragma unroll
    for (int mt = 0; mt < 2; ++mt) {
        #pragma unroll
        for (int ni = 0; ni < 4; ++ni)
            #pragma unroll
            for (int r = 0; r < 4; ++r) {
                float v = acc[mt][ni][r];
                v = v > 0.f ? v : 0.f;
                myh[(quad * 4 + r) * 72 + ni * 16 + l15] = f2bf(v);
            }
        f32x4 acc2[4];   // D2: col=lane&15 (=px), row=quad*4+reg (=cout)
        #pragma unroll
        for (int it = 0; it < 4; ++it)
            acc2[it] = (f32x4){b2q[it].x, b2q[it].y, b2q[it].z, b2q[it].w};
        #pragma unroll
        for (int k2 = 0; k2 < 2; ++k2) {
            const bf16x8 hb = *reinterpret_cast<const bf16x8*>(
                &myh[l15 * 72 + k2 * 32 + quad * 8]);
            #pragma unroll
            for (int it = 0; it < 4; ++it)
                acc2[it] = __builtin_amdgcn_mfma_f32_16x16x32_bf16(
                    wa2[k2][it], hb, acc2[it], 0, 0, 0);
        }
        const int gx = x0 + mt * 16 + l15;
        #pragma unroll
        for (int it = 0; it < 4; ++it)
            #pragma unroll
            for (int r = 0; r < 4; ++r) {
                const int o = it * 16 + quad * 4 + r;
                outg[(o * HH + gy) * WW + gx] = acc2[it][r];
            }
    }
}

// Fallback (workspace too small for xt): the verified baseline kernel.
__global__ __launch_bounds__(256, 3)
void mlpconv_kernel(const float* __restrict__ xin, const ushort* __restrict__ w1r,
                    const float* __restrict__ b1, const ushort* __restrict__ w2r,
                    const float* __restrict__ b2, float* __restrict__ out) {
    __shared__ ushort xs[10 * 40 * 64];

    const int tid = threadIdx.x;
    const int wave = tid >> 6;
    const int lane = tid & 63;
    const int l15 = lane & 15;
    const int quad = lane >> 4;

    const int x0 = blockIdx.x * 32;
    const int y0 = blockIdx.y * 8;
    const int b = blockIdx.z;

    const float* xg = xin + (size_t)b * (CIN * HH * WW);

    for (int e = tid; e < 6400; e += 256) {
        const int i = e % 10;
        const int t = e / 10;
        const int c = t & 63;
        const int r = t >> 6;
        const int gy = y0 + r - 1;
        const int gx4 = x0 - 4 + i * 4;
        float4 v = make_float4(0.f, 0.f, 0.f, 0.f);
        if (((unsigned)gy < (unsigned)HH) && ((unsigned)gx4 <= 220u))
            v = *reinterpret_cast<const float4*>(xg + (c * HH + gy) * WW + gx4);
        const int p0 = r * 40 + i * 4;
        xs[(p0 + 0) * 64 + (c ^ (((p0 + 0) & 7) * 8))] = f2bf(v.x);
        xs[(p0 + 1) * 64 + (c ^ (((p0 + 1) & 7) * 8))] = f2bf(v.y);
        xs[(p0 + 2) * 64 + (c ^ (((p0 + 2) & 7) * 8))] = f2bf(v.z);
        xs[(p0 + 3) * 64 + (c ^ (((p0 + 3) & 7) * 8))] = f2bf(v.w);
    }

    float b1v[4];
    #pragma unroll
    for (int nt = 0; nt < 4; ++nt) b1v[nt] = b1[nt * 16 + l15];

    f32x4 acc[4][4];
    #pragma unroll
    for (int mt = 0; mt < 4; ++mt)
        #pragma unroll
        for (int nt = 0; nt < 4; ++nt)
            acc[mt][nt] = (f32x4){b1v[nt], b1v[nt], b1v[nt], b1v[nt]};

    __syncthreads();

    #pragma unroll 2
    for (int ks = 0; ks < 18; ++ks) {
        const int ch = ks >> 1;
        const int s = ks & 1;
        const int dy = ch / 3, dx = ch - 3 * (ch / 3);
        const int ko = s * 32 + quad * 8;
        bf16x8 bfr[4];
        #pragma unroll
        for (int nt = 0; nt < 4; ++nt)
            bfr[nt] = *reinterpret_cast<const bf16x8*>(
                w1r + ch * 4096 + (nt * 16 + l15) * 64 + ko);
        const int kswz = ko ^ (((l15 + dx + 3) & 7) * 8);
        #pragma unroll
        for (int mt = 0; mt < 4; ++mt) {
            const int row = 2 * wave + (mt >> 1) + dy;
            const int col = (mt & 1) * 16 + l15 + dx + 3;
            const bf16x8 afr = *reinterpret_cast<const bf16x8*>(
                &xs[(row * 40 + col) * 64 + kswz]);
            #pragma unroll
            for (int nt = 0; nt < 4; ++nt)
                acc[mt][nt] = __builtin_amdgcn_mfma_f32_16x16x32_bf16(
                    afr, bfr[nt], acc[mt][nt], 0, 0, 0);
        }
    }

    __syncthreads();

    float4 b2q[4];
    #pragma unroll
    for (int it = 0; it < 4; ++it)
        b2q[it] = *reinterpret_cast<const float4*>(b2 + it * 16 + quad * 4);

    bf16x8 wa2[2][4];
    #pragma unroll
    for (int k2 = 0; k2 < 2; ++k2)
        #pragma unroll
        for (int it = 0; it < 4; ++it)
            wa2[k2][it] = *reinterpret_cast<const bf16x8*>(
                w2r + (it * 16 + l15) * 64 + k2 * 32 + quad * 8);

    ushort* myh = &xs[wave * (16 * 72)];
    float* outg = out + (size_t)b * (64 * HH * WW);

    #pragma unroll
    for (int mt = 0; mt < 4; ++mt) {
        #pragma unroll
        for (int ni = 0; ni < 4; ++ni)
            #pragma unroll
            for (int r = 0; r < 4; ++r) {
                float v = acc[mt][ni][r];
                v = v > 0.f ? v : 0.f;
                myh[(quad * 4 + r) * 72 + ni * 16 + l15] = f2bf(v);
            }
        f32x4 acc2[4];
        #pragma unroll
        for (int it = 0; it < 4; ++it)
            acc2[it] = (f32x4){b2q[it].x, b2q[it].y, b2q[it].z, b2q[it].w};
        #pragma unroll
        for (int k2 = 0; k2 < 2; ++k2) {
            const bf16x8 hb = *reinterpret_cast<const bf16x8*>(
                &myh[l15 * 72 + k2 * 32 + quad * 8]);
            #pragma unroll
            for (int it = 0; it < 4; ++it)
                acc2[it] = __builtin_amdgcn_mfma_f32_16x16x32_bf16(
                    wa2[k2][it], hb, acc2[it], 0, 0, 0);
        }
        const int gy = y0 + 2 * wave + (mt >> 1);
        const int gx = x0 + (mt & 1) * 16 + l15;
        #pragma unroll
        for (int it = 0; it < 4; ++it)
            #pragma unroll
            for (int r = 0; r < 4; ++r) {
                const int o = it * 16 + quad * 4 + r;
                outg[(o * HH + gy) * WW + gx] = acc2[it][r];
            }
    }
}

extern "C" void kernel_launch(void* const* d_in, const int* in_sizes, int n_in,
                              void* d_out, int out_size, void* d_ws, size_t ws_size,
                              hipStream_t stream) {
    const float* x  = (const float*)d_in[0];
    const float* W1 = (const float*)d_in[1];
    const float* b1 = (const float*)d_in[2];
    const float* W2 = (const float*)d_in[3];
    const float* b2 = (const float*)d_in[4];
    float* out = (float*)d_out;

    ushort* ws  = (ushort*)d_ws;
    ushort* w1r = ws;                 // 36,864 ushorts
    ushort* w2r = ws + 36864;         // 4,096 ushorts
    ushort* zp  = ws + 40960;         // 64 ushorts (zero page)
    ushort* xt  = ws + 41024;         // 8*HW*64 ushorts = 51.4 MB

    const size_t need = (size_t)41024 * 2 + (size_t)8 * HW * 64 * 2;
    const bool fast = ws_size >= need;

    prep_kernel<<<161, 256, 0, stream>>>(W1, W2, ws, fast ? 41024 : 40960);
    dim3 grid(WW / 32, HH / 8, 8);    // (7, 28, 8)
    if (fast) {
        xprep_kernel<<<dim3(392, 8), 256, 0, stream>>>(x, xt);
        mlpconv_fast<<<grid, dim3(512), 0, stream>>>(xt, w1r, b1, w2r, b2, zp, out);
    } else {
        mlpconv_kernel<<<grid, dim3(256), 0, stream>>>(x, w1r, b1, w2r, b2, out);
    }
}

// Round 6
// 300.463 us; speedup vs baseline: 1.1535x; 1.1535x over previous
//
#include <hip/hip_runtime.h>

typedef __attribute__((ext_vector_type(8))) short bf16x8;
typedef __attribute__((ext_vector_type(4))) float f32x4;

static constexpr int HH = 224, WW = 224;
static constexpr int CIN = 64;
static constexpr int HW = HH * WW;   // 50176

__device__ __forceinline__ ushort f2bf(float f) {
    unsigned u = __builtin_bit_cast(unsigned, f);
    u += 0x7FFFu + ((u >> 16) & 1u);   // round-to-nearest-even
    return (ushort)(u >> 16);
}

// ws layout (ushort units):
//   w1r  [0, 36864)        9*64*64 bf16, [ch][n][c]
//   w2r  [36864, 40960)    64*64 bf16
//   zp   [40960, 41024)    128 B of zeros (halo zero-page)
//   xt   [41024, +8*HW*64) x as bf16, [b][p=y*W+x][c]  (51.4 MB)
__global__ void prep_kernel(const float* __restrict__ W1, const float* __restrict__ W2,
                            ushort* __restrict__ ws, int nfill) {
    const int idx = blockIdx.x * 256 + threadIdx.x;
    if (idx < 36864) {
        const int ch = idx >> 12;
        const int n = (idx >> 6) & 63;
        const int c = idx & 63;
        ws[idx] = f2bf(W1[n * 576 + c * 9 + ch]);
    } else if (idx < 40960) {
        ws[idx] = f2bf(W2[idx - 36864]);
    } else if (idx < nfill) {
        ws[idx] = 0;
    }
}

// Transpose + convert: x fp32 [b][c][y][x] -> xt bf16 [b][p][c].
__global__ __launch_bounds__(256)
void xprep_kernel(const float* __restrict__ xin, ushort* __restrict__ xt) {
    const int b = blockIdx.y;
    const float* xg = xin + (size_t)b * (CIN * HW);
    ushort* xo = xt + (size_t)b * ((size_t)HW * 64);
    const int idx = blockIdx.x * 256 + threadIdx.x;   // [0, 100352)
    const int cg = idx & 7;                           // 8-channel group
    const int p4 = idx >> 3;                          // px/4 index [0, 12544)
    const float* src = xg + (size_t)(cg * 8) * HW + p4 * 4;
    float4 v[8];
    #pragma unroll
    for (int j = 0; j < 8; ++j)
        v[j] = *reinterpret_cast<const float4*>(src + (size_t)j * HW);
    #pragma unroll
    for (int k = 0; k < 4; ++k) {
        bf16x8 o;
        #pragma unroll
        for (int j = 0; j < 8; ++j)
            o[j] = (short)f2bf(reinterpret_cast<const float*>(&v[j])[k]);
        *reinterpret_cast<bf16x8*>(xo + (size_t)(p4 * 4 + k) * 64 + cg * 8) = o;
    }
}

#define GLD_LDS16(g, l) __builtin_amdgcn_global_load_lds(                  \
    (const __attribute__((address_space(1))) void*)(g),                    \
    (__attribute__((address_space(3))) void*)(l), 16, 0, 0)

// W1 fragment loader: one channel = 8 x 16B per lane (2 s-halves x 4 nt).
__device__ __forceinline__ void loadw_r(bf16x8 (&buf)[2][4],
                                        const ushort* __restrict__ w1r,
                                        int ch, int l15, int quad) {
    #pragma unroll
    for (int s = 0; s < 2; ++s)
        #pragma unroll
        for (int nt = 0; nt < 4; ++nt)
            buf[s][nt] = *reinterpret_cast<const bf16x8*>(
                w1r + ch * 4096 + (nt * 16 + l15) * 64 + s * 32 + quad * 8);
}

// One channel of MFMA work: 2 s-halves x 4 mt x 4 nt = 32 MFMAs.
__device__ __forceinline__ void step_r(const bf16x8 (&buf)[2][4],
                                       f32x4 (&acc)[4][4],
                                       const ushort* xs,
                                       int ch, int wave, int l15, int quad) {
    const int dy = ch / 3, dx = ch - 3 * (ch / 3);
    #pragma unroll
    for (int s = 0; s < 2; ++s) {
        const int ko = s * 32 + quad * 8;
        const int kswz = ko ^ (((l15 + dx + 3) & 7) * 8);
        #pragma unroll
        for (int mt = 0; mt < 4; ++mt) {
            const int row = 2 * wave + (mt >> 1) + dy;
            const int col = (mt & 1) * 16 + l15 + dx + 3;
            const bf16x8 afr = *reinterpret_cast<const bf16x8*>(
                &xs[(row * 40 + col) * 64 + kswz]);
            #pragma unroll
            for (int nt = 0; nt < 4; ++nt)
                acc[mt][nt] = __builtin_amdgcn_mfma_f32_16x16x32_bf16(
                    afr, buf[s][nt], acc[mt][nt], 0, 0, 0);
        }
    }
}

// Round-1 structure (4 waves x 64px x 64hid, acc[4][4]) + software-pipelined
// W1: named even/odd register buffers, prefetch ch+2 while computing ch.
// Load->use distance = one full channel body (32 MFMAs). Main loop kept as a
// runtime loop over channel-pairs (unroll 1) to bound scheduling-region size.
__global__ __launch_bounds__(256, 3)
void mlpconv_fast(const ushort* __restrict__ xt, const ushort* __restrict__ w1r,
                  const float* __restrict__ b1, const ushort* __restrict__ w2r,
                  const float* __restrict__ b2, const ushort* __restrict__ zp,
                  float* __restrict__ out) {
    __shared__ ushort xs[10 * 40 * 64];   // 51,200 B -> 3 blocks/CU

    const int tid = threadIdx.x;
    const int wave = tid >> 6;
    const int lane = tid & 63;
    const int l15 = lane & 15;
    const int quad = lane >> 4;

    const int x0 = blockIdx.x * 32;   // 7
    const int y0 = blockIdx.y * 8;    // 28
    const int b = blockIdx.z;         // 8

    const ushort* xtb = xt + (size_t)b * ((size_t)HW * 64);

    // Per-lane source swizzle (m173 pattern): lane l fills LDS slot
    // (px = l>>3, slot = l&7); slot s of px p holds channel-group s ^ (p&7).
    const int lpx = lane >> 3;
    const int laneoff = lpx * 64 + (((lane & 7) ^ lpx) * 8);   // ushort offset

    for (int q = wave; q < 50; q += 4) {     // 10 rows x 5 segments of 8 px
        const int r = q / 5;
        const int i = q - 5 * r;
        const int gy = y0 + r - 1;
        const int gx0 = x0 - 4 + i * 8;
        const ushort* real = xtb + (long)(gy * WW + gx0) * 64 + laneoff;
        const bool ok = ((unsigned)gy < (unsigned)HH) &
                        ((unsigned)(gx0 + lpx) < (unsigned)WW);
        const ushort* src = ok ? real : zp;   // halo lanes read the zero page
        GLD_LDS16(src, &xs[(r * 40 + i * 8) * 64]);
    }

    float b1v[4];
    #pragma unroll
    for (int nt = 0; nt < 4; ++nt) b1v[nt] = b1[nt * 16 + l15];

    f32x4 acc[4][4];   // C layout: col=lane&15 (=n), row=quad*4+reg (=m)
    #pragma unroll
    for (int mt = 0; mt < 4; ++mt)
        #pragma unroll
        for (int nt = 0; nt < 4; ++nt)
            acc[mt][nt] = (f32x4){b1v[nt], b1v[nt], b1v[nt], b1v[nt]};

    bf16x8 bA[2][4], bB[2][4];   // rotating W1 window: 64 VGPRs
    loadw_r(bA, w1r, 0, l15, quad);   // overlap W1 L2 latency with the DMA drain
    loadw_r(bB, w1r, 1, l15, quad);

    asm volatile("s_waitcnt vmcnt(0)" ::: "memory");
    __syncthreads();

    // ---- main loop: 3 channel-pairs + tail, barrier-free, 1-channel-ahead
    #pragma unroll 1
    for (int cp = 0; cp < 3; ++cp) {
        step_r(bA, acc, xs, 2 * cp,     wave, l15, quad);
        loadw_r(bA, w1r, 2 * cp + 2, l15, quad);
        step_r(bB, acc, xs, 2 * cp + 1, wave, l15, quad);
        loadw_r(bB, w1r, 2 * cp + 3, l15, quad);
    }
    step_r(bA, acc, xs, 6, wave, l15, quad);
    loadw_r(bA, w1r, 8, l15, quad);
    step_r(bB, acc, xs, 7, wave, l15, quad);
    step_r(bA, acc, xs, 8, wave, l15, quad);

    __syncthreads();   // other waves may still read xs; about to overwrite as h-scratch

    // ---- epilogue: ReLU -> bf16 h (per-wave LDS, no barrier) -> GEMM2 -> +b2 -> store
    float4 b2q[4];
    #pragma unroll
    for (int it = 0; it < 4; ++it)
        b2q[it] = *reinterpret_cast<const float4*>(b2 + it * 16 + quad * 4);

    bf16x8 wa2[2][4];   // W2 A-fragments, mt-invariant
    #pragma unroll
    for (int k2 = 0; k2 < 2; ++k2)
        #pragma unroll
        for (int it = 0; it < 4; ++it)
            wa2[k2][it] = *reinterpret_cast<const bf16x8*>(
                w2r + (it * 16 + l15) * 64 + k2 * 32 + quad * 8);

    ushort* myh = &xs[wave * (16 * 72)];
    float* outg = out + (size_t)b * (64 * HH * WW);

    #pragma unroll
    for (int mt = 0; mt < 4; ++mt) {
        #pragma unroll
        for (int ni = 0; ni < 4; ++ni)
            #pragma unroll
            for (int r = 0; r < 4; ++r) {
                float v = acc[mt][ni][r];
                v = v > 0.f ? v : 0.f;
                myh[(quad * 4 + r) * 72 + ni * 16 + l15] = f2bf(v);
            }
        f32x4 acc2[4];   // D2: col=lane&15 (=px), row=quad*4+reg (=cout)
        #pragma unroll
        for (int it = 0; it < 4; ++it)
            acc2[it] = (f32x4){b2q[it].x, b2q[it].y, b2q[it].z, b2q[it].w};
        #pragma unroll
        for (int k2 = 0; k2 < 2; ++k2) {
            const bf16x8 hb = *reinterpret_cast<const bf16x8*>(
                &myh[l15 * 72 + k2 * 32 + quad * 8]);
            #pragma unroll
            for (int it = 0; it < 4; ++it)
                acc2[it] = __builtin_amdgcn_mfma_f32_16x16x32_bf16(
                    wa2[k2][it], hb, acc2[it], 0, 0, 0);
        }
        const int gy = y0 + 2 * wave + (mt >> 1);
        const int gx = x0 + (mt & 1) * 16 + l15;
        #pragma unroll
        for (int it = 0; it < 4; ++it)
            #pragma unroll
            for (int r = 0; r < 4; ++r) {
                const int o = it * 16 + quad * 4 + r;
                outg[(o * HH + gy) * WW + gx] = acc2[it][r];
            }
    }
}

// Fallback (workspace too small for xt): the verified baseline kernel.
__global__ __launch_bounds__(256, 3)
void mlpconv_kernel(const float* __restrict__ xin, const ushort* __restrict__ w1r,
                    const float* __restrict__ b1, const ushort* __restrict__ w2r,
                    const float* __restrict__ b2, float* __restrict__ out) {
    __shared__ ushort xs[10 * 40 * 64];

    const int tid = threadIdx.x;
    const int wave = tid >> 6;
    const int lane = tid & 63;
    const int l15 = lane & 15;
    const int quad = lane >> 4;

    const int x0 = blockIdx.x * 32;
    const int y0 = blockIdx.y * 8;
    const int b = blockIdx.z;

    const float* xg = xin + (size_t)b * (CIN * HH * WW);

    for (int e = tid; e < 6400; e += 256) {
        const int i = e % 10;
        const int t = e / 10;
        const int c = t & 63;
        const int r = t >> 6;
        const int gy = y0 + r - 1;
        const int gx4 = x0 - 4 + i * 4;
        float4 v = make_float4(0.f, 0.f, 0.f, 0.f);
        if (((unsigned)gy < (unsigned)HH) && ((unsigned)gx4 <= 220u))
            v = *reinterpret_cast<const float4*>(xg + (c * HH + gy) * WW + gx4);
        const int p0 = r * 40 + i * 4;
        xs[(p0 + 0) * 64 + (c ^ (((p0 + 0) & 7) * 8))] = f2bf(v.x);
        xs[(p0 + 1) * 64 + (c ^ (((p0 + 1) & 7) * 8))] = f2bf(v.y);
        xs[(p0 + 2) * 64 + (c ^ (((p0 + 2) & 7) * 8))] = f2bf(v.z);
        xs[(p0 + 3) * 64 + (c ^ (((p0 + 3) & 7) * 8))] = f2bf(v.w);
    }

    float b1v[4];
    #pragma unroll
    for (int nt = 0; nt < 4; ++nt) b1v[nt] = b1[nt * 16 + l15];

    f32x4 acc[4][4];
    #pragma unroll
    for (int mt = 0; mt < 4; ++mt)
        #pragma unroll
        for (int nt = 0; nt < 4; ++nt)
            acc[mt][nt] = (f32x4){b1v[nt], b1v[nt], b1v[nt], b1v[nt]};

    __syncthreads();

    #pragma unroll 2
    for (int ks = 0; ks < 18; ++ks) {
        const int ch = ks >> 1;
        const int s = ks & 1;
        const int dy = ch / 3, dx = ch - 3 * (ch / 3);
        const int ko = s * 32 + quad * 8;
        bf16x8 bfr[4];
        #pragma unroll
        for (int nt = 0; nt < 4; ++nt)
            bfr[nt] = *reinterpret_cast<const bf16x8*>(
                w1r + ch * 4096 + (nt * 16 + l15) * 64 + ko);
        const int kswz = ko ^ (((l15 + dx + 3) & 7) * 8);
        #pragma unroll
        for (int mt = 0; mt < 4; ++mt) {
            const int row = 2 * wave + (mt >> 1) + dy;
            const int col = (mt & 1) * 16 + l15 + dx + 3;
            const bf16x8 afr = *reinterpret_cast<const bf16x8*>(
                &xs[(row * 40 + col) * 64 + kswz]);
            #pragma unroll
            for (int nt = 0; nt < 4; ++nt)
                acc[mt][nt] = __builtin_amdgcn_mfma_f32_16x16x32_bf16(
                    afr, bfr[nt], acc[mt][nt], 0, 0, 0);
        }
    }

    __syncthreads();

    float4 b2q[4];
    #pragma unroll
    for (int it = 0; it < 4; ++it)
        b2q[it] = *reinterpret_cast<const float4*>(b2 + it * 16 + quad * 4);

    bf16x8 wa2[2][4];
    #pragma unroll
    for (int k2 = 0; k2 < 2; ++k2)
        #pragma unroll
        for (int it = 0; it < 4; ++it)
            wa2[k2][it] = *reinterpret_cast<const bf16x8*>(
                w2r + (it * 16 + l15) * 64 + k2 * 32 + quad * 8);

    ushort* myh = &xs[wave * (16 * 72)];
    float* outg = out + (size_t)b * (64 * HH * WW);

    #pragma unroll
    for (int mt = 0; mt < 4; ++mt) {
        #pragma unroll
        for (int ni = 0; ni < 4; ++ni)
            #pragma unroll
            for (int r = 0; r < 4; ++r) {
                float v = acc[mt][ni][r];
                v = v > 0.f ? v : 0.f;
                myh[(quad * 4 + r) * 72 + ni * 16 + l15] = f2bf(v);
            }
        f32x4 acc2[4];
        #pragma unroll
        for (int it = 0; it < 4; ++it)
            acc2[it] = (f32x4){b2q[it].x, b2q[it].y, b2q[it].z, b2q[it].w};
        #pragma unroll
        for (int k2 = 0; k2 < 2; ++k2) {
            const bf16x8 hb = *reinterpret_cast<const bf16x8*>(
                &myh[l15 * 72 + k2 * 32 + quad * 8]);
            #pragma unroll
            for (int it = 0; it < 4; ++it)
                acc2[it] = __builtin_amdgcn_mfma_f32_16x16x32_bf16(
                    wa2[k2][it], hb, acc2[it], 0, 0, 0);
        }
        const int gy = y0 + 2 * wave + (mt >> 1);
        const int gx = x0 + (mt & 1) * 16 + l15;
        #pragma unroll
        for (int it = 0; it < 4; ++it)
            #pragma unroll
            for (int r = 0; r < 4; ++r) {
                const int o = it * 16 + quad * 4 + r;
                outg[(o * HH + gy) * WW + gx] = acc2[it][r];
            }
    }
}

extern "C" void kernel_launch(void* const* d_in, const int* in_sizes, int n_in,
                              void* d_out, int out_size, void* d_ws, size_t ws_size,
                              hipStream_t stream) {
    const float* x  = (const float*)d_in[0];
    const float* W1 = (const float*)d_in[1];
    const float* b1 = (const float*)d_in[2];
    const float* W2 = (const float*)d_in[3];
    const float* b2 = (const float*)d_in[4];
    float* out = (float*)d_out;

    ushort* ws  = (ushort*)d_ws;
    ushort* w1r = ws;                 // 36,864 ushorts
    ushort* w2r = ws + 36864;         // 4,096 ushorts
    ushort* zp  = ws + 40960;         // 64 ushorts (zero page)
    ushort* xt  = ws + 41024;         // 8*HW*64 ushorts = 51.4 MB

    const size_t need = (size_t)41024 * 2 + (size_t)8 * HW * 64 * 2;
    const bool fast = ws_size >= need;

    prep_kernel<<<161, 256, 0, stream>>>(W1, W2, ws, fast ? 41024 : 40960);
    dim3 grid(WW / 32, HH / 8, 8);    // (7, 28, 8)
    if (fast) {
        xprep_kernel<<<dim3(392, 8), 256, 0, stream>>>(x, xt);
        mlpconv_fast<<<grid, dim3(256), 0, stream>>>(xt, w1r, b1, w2r, b2, zp, out);
    } else {
        mlpconv_kernel<<<grid, dim3(256), 0, stream>>>(x, w1r, b1, w2r, b2, out);
    }
}

// Round 7
// 279.316 us; speedup vs baseline: 1.2408x; 1.0757x over previous
//
#include <hip/hip_runtime.h>

typedef __attribute__((ext_vector_type(8))) short bf16x8;
typedef __attribute__((ext_vector_type(4))) float f32x4;

static constexpr int HH = 224, WW = 224;
static constexpr int CIN = 64;
static constexpr int HW = HH * WW;   // 50176

__device__ __forceinline__ ushort f2bf(float f) {
    unsigned u = __builtin_bit_cast(unsigned, f);
    u += 0x7FFFu + ((u >> 16) & 1u);   // round-to-nearest-even
    return (ushort)(u >> 16);
}

// ws layout (ushort units):
//   w1r  [0, 36864)        9*64*64 bf16, [ch][n][c]
//   w2r  [36864, 40960)    64*64 bf16
//   zp   [40960, 41024)    128 B of zeros (halo zero-page)
//   xt   [41024, +8*HW*64) x as bf16, [b][p=y*W+x][c]  (51.4 MB)
__global__ void prep_kernel(const float* __restrict__ W1, const float* __restrict__ W2,
                            ushort* __restrict__ ws, int nfill) {
    const int idx = blockIdx.x * 256 + threadIdx.x;
    if (idx < 36864) {
        const int ch = idx >> 12;
        const int n = (idx >> 6) & 63;
        const int c = idx & 63;
        ws[idx] = f2bf(W1[n * 576 + c * 9 + ch]);
    } else if (idx < 40960) {
        ws[idx] = f2bf(W2[idx - 36864]);
    } else if (idx < nfill) {
        ws[idx] = 0;
    }
}

// Transpose + convert: x fp32 [b][c][y][x] -> xt bf16 [b][p][c].
__global__ __launch_bounds__(256)
void xprep_kernel(const float* __restrict__ xin, ushort* __restrict__ xt) {
    const int b = blockIdx.y;
    const float* xg = xin + (size_t)b * (CIN * HW);
    ushort* xo = xt + (size_t)b * ((size_t)HW * 64);
    const int idx = blockIdx.x * 256 + threadIdx.x;   // [0, 100352)
    const int cg = idx & 7;                           // 8-channel group
    const int p4 = idx >> 3;                          // px/4 index [0, 12544)
    const float* src = xg + (size_t)(cg * 8) * HW + p4 * 4;
    float4 v[8];
    #pragma unroll
    for (int j = 0; j < 8; ++j)
        v[j] = *reinterpret_cast<const float4*>(src + (size_t)j * HW);
    #pragma unroll
    for (int k = 0; k < 4; ++k) {
        bf16x8 o;
        #pragma unroll
        for (int j = 0; j < 8; ++j)
            o[j] = (short)f2bf(reinterpret_cast<const float*>(&v[j])[k]);
        *reinterpret_cast<bf16x8*>(xo + (size_t)(p4 * 4 + k) * 64 + cg * 8) = o;
    }
}

#define GLD_LDS16(g, l) __builtin_amdgcn_global_load_lds(                  \
    (const __attribute__((address_space(1))) void*)(g),                    \
    (__attribute__((address_space(3))) void*)(l), 16, 0, 0)

// Round-1 verified structure (4 waves x 64px x 64hid, acc[4][4], unroll-2
// k-loop, compiler-scheduled W1 loads) + swapped-operand GEMM2 epilogue:
// mfma(h, W2) puts px in the register dim -> float4 output stores
// (16 dwordx4/wave instead of 64 scalar stores).
__global__ __launch_bounds__(256, 3)
void mlpconv_fast(const ushort* __restrict__ xt, const ushort* __restrict__ w1r,
                  const float* __restrict__ b1, const ushort* __restrict__ w2r,
                  const float* __restrict__ b2, const ushort* __restrict__ zp,
                  float* __restrict__ out) {
    __shared__ ushort xs[10 * 40 * 64];   // 51,200 B -> 3 blocks/CU

    const int tid = threadIdx.x;
    const int wave = tid >> 6;
    const int lane = tid & 63;
    const int l15 = lane & 15;
    const int quad = lane >> 4;

    const int x0 = blockIdx.x * 32;   // 7
    const int y0 = blockIdx.y * 8;    // 28
    const int b = blockIdx.z;         // 8

    const ushort* xtb = xt + (size_t)b * ((size_t)HW * 64);

    // Per-lane source swizzle (m173 pattern): lane l fills LDS slot
    // (px = l>>3, slot = l&7); slot s of px p holds channel-group s ^ (p&7).
    const int lpx = lane >> 3;
    const int laneoff = lpx * 64 + (((lane & 7) ^ lpx) * 8);   // ushort offset

    for (int q = wave; q < 50; q += 4) {     // 10 rows x 5 segments of 8 px
        const int r = q / 5;
        const int i = q - 5 * r;
        const int gy = y0 + r - 1;
        const int gx0 = x0 - 4 + i * 8;
        const ushort* real = xtb + (long)(gy * WW + gx0) * 64 + laneoff;
        const bool ok = ((unsigned)gy < (unsigned)HH) &
                        ((unsigned)(gx0 + lpx) < (unsigned)WW);
        const ushort* src = ok ? real : zp;   // halo lanes read the zero page
        GLD_LDS16(src, &xs[(r * 40 + i * 8) * 64]);
    }

    float b1v[4];
    #pragma unroll
    for (int nt = 0; nt < 4; ++nt) b1v[nt] = b1[nt * 16 + l15];

    f32x4 acc[4][4];   // C layout: col=lane&15 (=n hid), row=quad*4+reg (=m px)
    #pragma unroll
    for (int mt = 0; mt < 4; ++mt)
        #pragma unroll
        for (int nt = 0; nt < 4; ++nt)
            acc[mt][nt] = (f32x4){b1v[nt], b1v[nt], b1v[nt], b1v[nt]};

    asm volatile("s_waitcnt vmcnt(0)" ::: "memory");
    __syncthreads();

    // ---- main loop: 18 k-steps (9 taps x 2 halves of 32 ch), barrier-free.
    // Round-1 form: compiler schedules bfr loads across the unroll-2 window.
    #pragma unroll 2
    for (int ks = 0; ks < 18; ++ks) {
        const int ch = ks >> 1;
        const int s = ks & 1;
        const int dy = ch / 3, dx = ch - 3 * (ch / 3);
        const int ko = s * 32 + quad * 8;
        bf16x8 bfr[4];
        #pragma unroll
        for (int nt = 0; nt < 4; ++nt)
            bfr[nt] = *reinterpret_cast<const bf16x8*>(
                w1r + ch * 4096 + (nt * 16 + l15) * 64 + ko);
        const int kswz = ko ^ (((l15 + dx + 3) & 7) * 8);
        #pragma unroll
        for (int mt = 0; mt < 4; ++mt) {
            const int row = 2 * wave + (mt >> 1) + dy;
            const int col = (mt & 1) * 16 + l15 + dx + 3;
            const bf16x8 afr = *reinterpret_cast<const bf16x8*>(
                &xs[(row * 40 + col) * 64 + kswz]);
            #pragma unroll
            for (int nt = 0; nt < 4; ++nt)
                acc[mt][nt] = __builtin_amdgcn_mfma_f32_16x16x32_bf16(
                    afr, bfr[nt], acc[mt][nt], 0, 0, 0);
        }
    }

    __syncthreads();   // other waves may still read xs; about to overwrite as h-scratch

    // ---- epilogue: ReLU -> bf16 h (per-wave LDS) -> GEMM2 (h as A, W2 as B)
    //      -> +b2 -> float4 stores.
    // Swapped operands: D2 row = quad*4+reg = px (consecutive!), col = l15 = cout.
    float b2v[4];
    #pragma unroll
    for (int it = 0; it < 4; ++it) b2v[it] = b2[it * 16 + l15];

    bf16x8 wa2[2][4];   // W2 fragments: lane l15 = cout col, quad*8+j = k  (B operand)
    #pragma unroll
    for (int k2 = 0; k2 < 2; ++k2)
        #pragma unroll
        for (int it = 0; it < 4; ++it)
            wa2[k2][it] = *reinterpret_cast<const bf16x8*>(
                w2r + (it * 16 + l15) * 64 + k2 * 32 + quad * 8);

    ushort* myh = &xs[wave * (16 * 72)];
    float* outg = out + (size_t)b * (64 * HH * WW);

    #pragma unroll
    for (int mt = 0; mt < 4; ++mt) {
        #pragma unroll
        for (int ni = 0; ni < 4; ++ni)
            #pragma unroll
            for (int r = 0; r < 4; ++r) {
                float v = acc[mt][ni][r];
                v = v > 0.f ? v : 0.f;
                myh[(quad * 4 + r) * 72 + ni * 16 + l15] = f2bf(v);
            }
        f32x4 acc2[4];   // D2: row=quad*4+reg (=px), col=lane&15 (=cout)
        #pragma unroll
        for (int it = 0; it < 4; ++it)
            acc2[it] = (f32x4){b2v[it], b2v[it], b2v[it], b2v[it]};
        #pragma unroll
        for (int k2 = 0; k2 < 2; ++k2) {
            const bf16x8 hb = *reinterpret_cast<const bf16x8*>(
                &myh[l15 * 72 + k2 * 32 + quad * 8]);   // A: lane=px row, quad*8+j=k
            #pragma unroll
            for (int it = 0; it < 4; ++it)
                acc2[it] = __builtin_amdgcn_mfma_f32_16x16x32_bf16(
                    hb, wa2[k2][it], acc2[it], 0, 0, 0);
        }
        const int gy = y0 + 2 * wave + (mt >> 1);
        const int gxb = x0 + (mt & 1) * 16 + quad * 4;
        #pragma unroll
        for (int it = 0; it < 4; ++it) {
            const int o = it * 16 + l15;
            *reinterpret_cast<f32x4*>(outg + ((size_t)o * HH + gy) * WW + gxb)
                = acc2[it];
        }
    }
}

// Fallback (workspace too small for xt): the verified baseline kernel.
__global__ __launch_bounds__(256, 3)
void mlpconv_kernel(const float* __restrict__ xin, const ushort* __restrict__ w1r,
                    const float* __restrict__ b1, const ushort* __restrict__ w2r,
                    const float* __restrict__ b2, float* __restrict__ out) {
    __shared__ ushort xs[10 * 40 * 64];

    const int tid = threadIdx.x;
    const int wave = tid >> 6;
    const int lane = tid & 63;
    const int l15 = lane & 15;
    const int quad = lane >> 4;

    const int x0 = blockIdx.x * 32;
    const int y0 = blockIdx.y * 8;
    const int b = blockIdx.z;

    const float* xg = xin + (size_t)b * (CIN * HH * WW);

    for (int e = tid; e < 6400; e += 256) {
        const int i = e % 10;
        const int t = e / 10;
        const int c = t & 63;
        const int r = t >> 6;
        const int gy = y0 + r - 1;
        const int gx4 = x0 - 4 + i * 4;
        float4 v = make_float4(0.f, 0.f, 0.f, 0.f);
        if (((unsigned)gy < (unsigned)HH) && ((unsigned)gx4 <= 220u))
            v = *reinterpret_cast<const float4*>(xg + (c * HH + gy) * WW + gx4);
        const int p0 = r * 40 + i * 4;
        xs[(p0 + 0) * 64 + (c ^ (((p0 + 0) & 7) * 8))] = f2bf(v.x);
        xs[(p0 + 1) * 64 + (c ^ (((p0 + 1) & 7) * 8))] = f2bf(v.y);
        xs[(p0 + 2) * 64 + (c ^ (((p0 + 2) & 7) * 8))] = f2bf(v.z);
        xs[(p0 + 3) * 64 + (c ^ (((p0 + 3) & 7) * 8))] = f2bf(v.w);
    }

    float b1v[4];
    #pragma unroll
    for (int nt = 0; nt < 4; ++nt) b1v[nt] = b1[nt * 16 + l15];

    f32x4 acc[4][4];
    #pragma unroll
    for (int mt = 0; mt < 4; ++mt)
        #pragma unroll
        for (int nt = 0; nt < 4; ++nt)
            acc[mt][nt] = (f32x4){b1v[nt], b1v[nt], b1v[nt], b1v[nt]};

    __syncthreads();

    #pragma unroll 2
    for (int ks = 0; ks < 18; ++ks) {
        const int ch = ks >> 1;
        const int s = ks & 1;
        const int dy = ch / 3, dx = ch - 3 * (ch / 3);
        const int ko = s * 32 + quad * 8;
        bf16x8 bfr[4];
        #pragma unroll
        for (int nt = 0; nt < 4; ++nt)
            bfr[nt] = *reinterpret_cast<const bf16x8*>(
                w1r + ch * 4096 + (nt * 16 + l15) * 64 + ko);
        const int kswz = ko ^ (((l15 + dx + 3) & 7) * 8);
        #pragma unroll
        for (int mt = 0; mt < 4; ++mt) {
            const int row = 2 * wave + (mt >> 1) + dy;
            const int col = (mt & 1) * 16 + l15 + dx + 3;
            const bf16x8 afr = *reinterpret_cast<const bf16x8*>(
                &xs[(row * 40 + col) * 64 + kswz]);
            #pragma unroll
            for (int nt = 0; nt < 4; ++nt)
                acc[mt][nt] = __builtin_amdgcn_mfma_f32_16x16x32_bf16(
                    afr, bfr[nt], acc[mt][nt], 0, 0, 0);
        }
    }

    __syncthreads();

    float4 b2q[4];
    #pragma unroll
    for (int it = 0; it < 4; ++it)
        b2q[it] = *reinterpret_cast<const float4*>(b2 + it * 16 + quad * 4);

    bf16x8 wa2[2][4];
    #pragma unroll
    for (int k2 = 0; k2 < 2; ++k2)
        #pragma unroll
        for (int it = 0; it < 4; ++it)
            wa2[k2][it] = *reinterpret_cast<const bf16x8*>(
                w2r + (it * 16 + l15) * 64 + k2 * 32 + quad * 8);

    ushort* myh = &xs[wave * (16 * 72)];
    float* outg = out + (size_t)b * (64 * HH * WW);

    #pragma unroll
    for (int mt = 0; mt < 4; ++mt) {
        #pragma unroll
        for (int ni = 0; ni < 4; ++ni)
            #pragma unroll
            for (int r = 0; r < 4; ++r) {
                float v = acc[mt][ni][r];
                v = v > 0.f ? v : 0.f;
                myh[(quad * 4 + r) * 72 + ni * 16 + l15] = f2bf(v);
            }
        f32x4 acc2[4];
        #pragma unroll
        for (int it = 0; it < 4; ++it)
            acc2[it] = (f32x4){b2q[it].x, b2q[it].y, b2q[it].z, b2q[it].w};
        #pragma unroll
        for (int k2 = 0; k2 < 2; ++k2) {
            const bf16x8 hb = *reinterpret_cast<const bf16x8*>(
                &myh[l15 * 72 + k2 * 32 + quad * 8]);
            #pragma unroll
            for (int it = 0; it < 4; ++it)
                acc2[it] = __builtin_amdgcn_mfma_f32_16x16x32_bf16(
                    wa2[k2][it], hb, acc2[it], 0, 0, 0);
        }
        const int gy = y0 + 2 * wave + (mt >> 1);
        const int gx = x0 + (mt & 1) * 16 + l15;
        #pragma unroll
        for (int it = 0; it < 4; ++it)
            #pragma unroll
            for (int r = 0; r < 4; ++r) {
                const int o = it * 16 + quad * 4 + r;
                outg[(o * HH + gy) * WW + gx] = acc2[it][r];
            }
    }
}

extern "C" void kernel_launch(void* const* d_in, const int* in_sizes, int n_in,
                              void* d_out, int out_size, void* d_ws, size_t ws_size,
                              hipStream_t stream) {
    const float* x  = (const float*)d_in[0];
    const float* W1 = (const float*)d_in[1];
    const float* b1 = (const float*)d_in[2];
    const float* W2 = (const float*)d_in[3];
    const float* b2 = (const float*)d_in[4];
    float* out = (float*)d_out;

    ushort* ws  = (ushort*)d_ws;
    ushort* w1r = ws;                 // 36,864 ushorts
    ushort* w2r = ws + 36864;         // 4,096 ushorts
    ushort* zp  = ws + 40960;         // 64 ushorts (zero page)
    ushort* xt  = ws + 41024;         // 8*HW*64 ushorts = 51.4 MB

    const size_t need = (size_t)41024 * 2 + (size_t)8 * HW * 64 * 2;
    const bool fast = ws_size >= need;

    prep_kernel<<<161, 256, 0, stream>>>(W1, W2, ws, fast ? 41024 : 40960);
    dim3 grid(WW / 32, HH / 8, 8);    // (7, 28, 8)
    if (fast) {
        xprep_kernel<<<dim3(392, 8), 256, 0, stream>>>(x, xt);
        mlpconv_fast<<<grid, dim3(256), 0, stream>>>(xt, w1r, b1, w2r, b2, zp, out);
    } else {
        mlpconv_kernel<<<grid, dim3(256), 0, stream>>>(x, w1r, b1, w2r, b2, out);
    }
}

// Round 9
// 249.776 us; speedup vs baseline: 1.3876x; 1.1183x over previous
//
#include <hip/hip_runtime.h>

typedef __attribute__((ext_vector_type(8))) short bf16x8;
typedef __attribute__((ext_vector_type(4))) float f32x4;

static constexpr int HH = 224, WW = 224;
static constexpr int CIN = 64;
static constexpr int HW = HH * WW;   // 50176

__device__ __forceinline__ ushort f2bf(float f) {
    unsigned u = __builtin_bit_cast(unsigned, f);
    u += 0x7FFFu + ((u >> 16) & 1u);   // round-to-nearest-even
    return (ushort)(u >> 16);
}

// ws layout (ushort units):
//   w1r  [0, 36864)        9*64*64 bf16, [ch][n][c]           (fallback kernel)
//   w2r  [36864, 40960)    64*64 bf16
//   zp   [40960, 41024)    128 B of zeros (halo zero-page)
//   w1x  [41024, 77888)    W1 fragment-contiguous: [(ch*8+s*4+nt)][lane][j]
//                          lane=quad*16+l15, j=0..7 -> every k-loop load is
//                          one contiguous 1KB wave-read (no 128B-stride gather)
//   xt   [77888, +8*HW*64) x as bf16, [b][p=y*W+x][c]  (51.4 MB)
__global__ void prep_kernel(const float* __restrict__ W1, const float* __restrict__ W2,
                            ushort* __restrict__ ws, int nfill) {
    const int idx = blockIdx.x * 256 + threadIdx.x;
    if (idx < 36864) {
        const int ch = idx >> 12;
        const int n = (idx >> 6) & 63;
        const int c = idx & 63;
        ws[idx] = f2bf(W1[n * 576 + c * 9 + ch]);
    } else if (idx < 40960) {
        ws[idx] = f2bf(W2[idx - 36864]);
    } else if (idx < 41024) {
        if (idx < nfill) ws[idx] = 0;
    } else if (idx < nfill) {          // 41024..77888: w1x
        const int k = idx - 41024;
        const int j = k & 7;
        const int l15 = (k >> 3) & 15;
        const int quad = (k >> 7) & 3;
        const int nt = (k >> 9) & 3;
        const int s = (k >> 11) & 1;
        const int ch = k >> 12;
        const int n = nt * 16 + l15;
        const int c = s * 32 + quad * 8 + j;
        ws[idx] = f2bf(W1[n * 576 + c * 9 + ch]);
    }
}

// Transpose + convert: x fp32 [b][c][y][x] -> xt bf16 [b][p][c].
__global__ __launch_bounds__(256)
void xprep_kernel(const float* __restrict__ xin, ushort* __restrict__ xt) {
    const int b = blockIdx.y;
    const float* xg = xin + (size_t)b * (CIN * HW);
    ushort* xo = xt + (size_t)b * ((size_t)HW * 64);
    const int idx = blockIdx.x * 256 + threadIdx.x;   // [0, 100352)
    const int cg = idx & 7;                           // 8-channel group
    const int p4 = idx >> 3;                          // px/4 index [0, 12544)
    const float* src = xg + (size_t)(cg * 8) * HW + p4 * 4;
    float4 v[8];
    #pragma unroll
    for (int j = 0; j < 8; ++j)
        v[j] = *reinterpret_cast<const float4*>(src + (size_t)j * HW);
    #pragma unroll
    for (int k = 0; k < 4; ++k) {
        bf16x8 o;
        #pragma unroll
        for (int j = 0; j < 8; ++j)
            o[j] = (short)f2bf(reinterpret_cast<const float*>(&v[j])[k]);
        *reinterpret_cast<bf16x8*>(xo + (size_t)(p4 * 4 + k) * 64 + cg * 8) = o;
    }
}

#define GLD_LDS16(g, l) __builtin_amdgcn_global_load_lds(                  \
    (const __attribute__((address_space(1))) void*)(g),                    \
    (__attribute__((address_space(3))) void*)(l), 16, 0, 0)

// Round-1 verified structure (4 waves x 64px x 64hid, acc[4][4], unroll-2
// k-loop) + r7 float4-store epilogue + fragment-contiguous W1 loads:
// bfr address = w1x + ks*2048 + nt*512 + lane*8  (1KB contiguous per wave).
__global__ __launch_bounds__(256, 3)
void mlpconv_fast(const ushort* __restrict__ xt, const ushort* __restrict__ w1x,
                  const float* __restrict__ b1, const ushort* __restrict__ w2r,
                  const float* __restrict__ b2, const ushort* __restrict__ zp,
                  float* __restrict__ out) {
    __shared__ ushort xs[10 * 40 * 64];   // 51,200 B -> 3 blocks/CU

    const int tid = threadIdx.x;
    const int wave = tid >> 6;
    const int lane = tid & 63;
    const int l15 = lane & 15;
    const int quad = lane >> 4;

    const int x0 = blockIdx.x * 32;   // 7
    const int y0 = blockIdx.y * 8;    // 28
    const int b = blockIdx.z;         // 8

    const ushort* xtb = xt + (size_t)b * ((size_t)HW * 64);

    // Per-lane source swizzle (m173 pattern): lane l fills LDS slot
    // (px = l>>3, slot = l&7); slot s of px p holds channel-group s ^ (p&7).
    const int lpx = lane >> 3;
    const int laneoff = lpx * 64 + (((lane & 7) ^ lpx) * 8);   // ushort offset

    for (int q = wave; q < 50; q += 4) {     // 10 rows x 5 segments of 8 px
        const int r = q / 5;
        const int i = q - 5 * r;
        const int gy = y0 + r - 1;
        const int gx0 = x0 - 4 + i * 8;
        const ushort* real = xtb + (long)(gy * WW + gx0) * 64 + laneoff;
        const bool ok = ((unsigned)gy < (unsigned)HH) &
                        ((unsigned)(gx0 + lpx) < (unsigned)WW);
        const ushort* src = ok ? real : zp;   // halo lanes read the zero page
        GLD_LDS16(src, &xs[(r * 40 + i * 8) * 64]);
    }

    float b1v[4];
    #pragma unroll
    for (int nt = 0; nt < 4; ++nt) b1v[nt] = b1[nt * 16 + l15];

    f32x4 acc[4][4];   // C layout: col=lane&15 (=n hid), row=quad*4+reg (=m px)
    #pragma unroll
    for (int mt = 0; mt < 4; ++mt)
        #pragma unroll
        for (int nt = 0; nt < 4; ++nt)
            acc[mt][nt] = (f32x4){b1v[nt], b1v[nt], b1v[nt], b1v[nt]};

    asm volatile("s_waitcnt vmcnt(0)" ::: "memory");
    __syncthreads();

    // ---- main loop: 18 k-steps (9 taps x 2 halves of 32 ch), barrier-free.
    #pragma unroll 2
    for (int ks = 0; ks < 18; ++ks) {
        const int ch = ks >> 1;
        const int s = ks & 1;
        const int dy = ch / 3, dx = ch - 3 * (ch / 3);
        const int ko = s * 32 + quad * 8;
        bf16x8 bfr[4];
        #pragma unroll
        for (int nt = 0; nt < 4; ++nt)
            bfr[nt] = *reinterpret_cast<const bf16x8*>(
                w1x + ks * 2048 + nt * 512 + lane * 8);   // contiguous 1KB/wave
        const int kswz = ko ^ (((l15 + dx + 3) & 7) * 8);
        #pragma unroll
        for (int mt = 0; mt < 4; ++mt) {
            const int row = 2 * wave + (mt >> 1) + dy;
            const int col = (mt & 1) * 16 + l15 + dx + 3;
            const bf16x8 afr = *reinterpret_cast<const bf16x8*>(
                &xs[(row * 40 + col) * 64 + kswz]);
            #pragma unroll
            for (int nt = 0; nt < 4; ++nt)
                acc[mt][nt] = __builtin_amdgcn_mfma_f32_16x16x32_bf16(
                    afr, bfr[nt], acc[mt][nt], 0, 0, 0);
        }
    }

    __syncthreads();   // other waves may still read xs; about to overwrite as h-scratch

    // ---- epilogue: ReLU -> bf16 h (per-wave LDS) -> GEMM2 (h as A, W2 as B)
    //      -> +b2 -> float4 stores.
    float b2v[4];
    #pragma unroll
    for (int it = 0; it < 4; ++it) b2v[it] = b2[it * 16 + l15];

    bf16x8 wa2[2][4];   // W2 fragments: lane l15 = cout col, quad*8+j = k (B operand)
    #pragma unroll
    for (int k2 = 0; k2 < 2; ++k2)
        #pragma unroll
        for (int it = 0; it < 4; ++it)
            wa2[k2][it] = *reinterpret_cast<const bf16x8*>(
                w2r + (it * 16 + l15) * 64 + k2 * 32 + quad * 8);

    ushort* myh = &xs[wave * (16 * 72)];
    float* outg = out + (size_t)b * (64 * HH * WW);

    #pragma unroll
    for (int mt = 0; mt < 4; ++mt) {
        #pragma unroll
        for (int ni = 0; ni < 4; ++ni)
            #pragma unroll
            for (int r = 0; r < 4; ++r) {
                float v = acc[mt][ni][r];
                v = v > 0.f ? v : 0.f;
                myh[(quad * 4 + r) * 72 + ni * 16 + l15] = f2bf(v);
            }
        f32x4 acc2[4];   // D2: row=quad*4+reg (=px), col=lane&15 (=cout)
        #pragma unroll
        for (int it = 0; it < 4; ++it)
            acc2[it] = (f32x4){b2v[it], b2v[it], b2v[it], b2v[it]};
        #pragma unroll
        for (int k2 = 0; k2 < 2; ++k2) {
            const bf16x8 hb = *reinterpret_cast<const bf16x8*>(
                &myh[l15 * 72 + k2 * 32 + quad * 8]);   // A: lane=px row, quad*8+j=k
            #pragma unroll
            for (int it = 0; it < 4; ++it)
                acc2[it] = __builtin_amdgcn_mfma_f32_16x16x32_bf16(
                    hb, wa2[k2][it], acc2[it], 0, 0, 0);
        }
        const int gy = y0 + 2 * wave + (mt >> 1);
        const int gxb = x0 + (mt & 1) * 16 + quad * 4;
        #pragma unroll
        for (int it = 0; it < 4; ++it) {
            const int o = it * 16 + l15;
            *reinterpret_cast<f32x4*>(outg + ((size_t)o * HH + gy) * WW + gxb)
                = acc2[it];
        }
    }
}

// Fallback (workspace too small for xt): the verified baseline kernel (old w1r layout).
__global__ __launch_bounds__(256, 3)
void mlpconv_kernel(const float* __restrict__ xin, const ushort* __restrict__ w1r,
                    const float* __restrict__ b1, const ushort* __restrict__ w2r,
                    const float* __restrict__ b2, float* __restrict__ out) {
    __shared__ ushort xs[10 * 40 * 64];

    const int tid = threadIdx.x;
    const int wave = tid >> 6;
    const int lane = tid & 63;
    const int l15 = lane & 15;
    const int quad = lane >> 4;

    const int x0 = blockIdx.x * 32;
    const int y0 = blockIdx.y * 8;
    const int b = blockIdx.z;

    const float* xg = xin + (size_t)b * (CIN * HH * WW);

    for (int e = tid; e < 6400; e += 256) {
        const int i = e % 10;
        const int t = e / 10;
        const int c = t & 63;
        const int r = t >> 6;
        const int gy = y0 + r - 1;
        const int gx4 = x0 - 4 + i * 4;
        float4 v = make_float4(0.f, 0.f, 0.f, 0.f);
        if (((unsigned)gy < (unsigned)HH) && ((unsigned)gx4 <= 220u))
            v = *reinterpret_cast<const float4*>(xg + (c * HH + gy) * WW + gx4);
        const int p0 = r * 40 + i * 4;
        xs[(p0 + 0) * 64 + (c ^ (((p0 + 0) & 7) * 8))] = f2bf(v.x);
        xs[(p0 + 1) * 64 + (c ^ (((p0 + 1) & 7) * 8))] = f2bf(v.y);
        xs[(p0 + 2) * 64 + (c ^ (((p0 + 2) & 7) * 8))] = f2bf(v.z);
        xs[(p0 + 3) * 64 + (c ^ (((p0 + 3) & 7) * 8))] = f2bf(v.w);
    }

    float b1v[4];
    #pragma unroll
    for (int nt = 0; nt < 4; ++nt) b1v[nt] = b1[nt * 16 + l15];

    f32x4 acc[4][4];
    #pragma unroll
    for (int mt = 0; mt < 4; ++mt)
        #pragma unroll
        for (int nt = 0; nt < 4; ++nt)
            acc[mt][nt] = (f32x4){b1v[nt], b1v[nt], b1v[nt], b1v[nt]};

    __syncthreads();

    #pragma unroll 2
    for (int ks = 0; ks < 18; ++ks) {
        const int ch = ks >> 1;
        const int s = ks & 1;
        const int dy = ch / 3, dx = ch - 3 * (ch / 3);
        const int ko = s * 32 + quad * 8;
        bf16x8 bfr[4];
        #pragma unroll
        for (int nt = 0; nt < 4; ++nt)
            bfr[nt] = *reinterpret_cast<const bf16x8*>(
                w1r + ch * 4096 + (nt * 16 + l15) * 64 + ko);
        const int kswz = ko ^ (((l15 + dx + 3) & 7) * 8);
        #pragma unroll
        for (int mt = 0; mt < 4; ++mt) {
            const int row = 2 * wave + (mt >> 1) + dy;
            const int col = (mt & 1) * 16 + l15 + dx + 3;
            const bf16x8 afr = *reinterpret_cast<const bf16x8*>(
                &xs[(row * 40 + col) * 64 + kswz]);
            #pragma unroll
            for (int nt = 0; nt < 4; ++nt)
                acc[mt][nt] = __builtin_amdgcn_mfma_f32_16x16x32_bf16(
                    afr, bfr[nt], acc[mt][nt], 0, 0, 0);
        }
    }

    __syncthreads();

    float4 b2q[4];
    #pragma unroll
    for (int it = 0; it < 4; ++it)
        b2q[it] = *reinterpret_cast<const float4*>(b2 + it * 16 + quad * 4);

    bf16x8 wa2[2][4];
    #pragma unroll
    for (int k2 = 0; k2 < 2; ++k2)
        #pragma unroll
        for (int it = 0; it < 4; ++it)
            wa2[k2][it] = *reinterpret_cast<const bf16x8*>(
                w2r + (it * 16 + l15) * 64 + k2 * 32 + quad * 8);

    ushort* myh = &xs[wave * (16 * 72)];
    float* outg = out + (size_t)b * (64 * HH * WW);

    #pragma unroll
    for (int mt = 0; mt < 4; ++mt) {
        #pragma unroll
        for (int ni = 0; ni < 4; ++ni)
            #pragma unroll
            for (int r = 0; r < 4; ++r) {
                float v = acc[mt][ni][r];
                v = v > 0.f ? v : 0.f;
                myh[(quad * 4 + r) * 72 + ni * 16 + l15] = f2bf(v);
            }
        f32x4 acc2[4];
        #pragma unroll
        for (int it = 0; it < 4; ++it)
            acc2[it] = (f32x4){b2q[it].x, b2q[it].y, b2q[it].z, b2q[it].w};
        #pragma unroll
        for (int k2 = 0; k2 < 2; ++k2) {
            const bf16x8 hb = *reinterpret_cast<const bf16x8*>(
                &myh[l15 * 72 + k2 * 32 + quad * 8]);
            #pragma unroll
            for (int it = 0; it < 4; ++it)
                acc2[it] = __builtin_amdgcn_mfma_f32_16x16x32_bf16(
                    wa2[k2][it], hb, acc2[it], 0, 0, 0);
        }
        const int gy = y0 + 2 * wave + (mt >> 1);
        const int gx = x0 + (mt & 1) * 16 + l15;
        #pragma unroll
        for (int it = 0; it < 4; ++it)
            #pragma unroll
            for (int r = 0; r < 4; ++r) {
                const int o = it * 16 + quad * 4 + r;
                outg[(o * HH + gy) * WW + gx] = acc2[it][r];
            }
    }
}

extern "C" void kernel_launch(void* const* d_in, const int* in_sizes, int n_in,
                              void* d_out, int out_size, void* d_ws, size_t ws_size,
                              hipStream_t stream) {
    const float* x  = (const float*)d_in[0];
    const float* W1 = (const float*)d_in[1];
    const float* b1 = (const float*)d_in[2];
    const float* W2 = (const float*)d_in[3];
    const float* b2 = (const float*)d_in[4];
    float* out = (float*)d_out;

    ushort* ws  = (ushort*)d_ws;
    ushort* w1r = ws;                 // 36,864 ushorts (fallback layout)
    ushort* w2r = ws + 36864;         // 4,096 ushorts
    ushort* zp  = ws + 40960;         // 64 ushorts (zero page)
    ushort* w1x = ws + 41024;         // 36,864 ushorts (fragment-contiguous)
    ushort* xt  = ws + 77888;         // 8*HW*64 ushorts = 51.4 MB

    const size_t need = (size_t)77888 * 2 + (size_t)8 * HW * 64 * 2;
    const bool fast = ws_size >= need;

    prep_kernel<<<305, 256, 0, stream>>>(W1, W2, ws, fast ? 77888 : 40960);
    dim3 grid(WW / 32, HH / 8, 8);    // (7, 28, 8)
    if (fast) {
        xprep_kernel<<<dim3(392, 8), 256, 0, stream>>>(x, xt);
        mlpconv_fast<<<grid, dim3(256), 0, stream>>>(xt, w1x, b1, w2r, b2, zp, out);
    } else {
        mlpconv_kernel<<<grid, dim3(256), 0, stream>>>(x, w1r, b1, w2r, b2, out);
    }
}

// Round 10
// 249.552 us; speedup vs baseline: 1.3888x; 1.0009x over previous
//
#include <hip/hip_runtime.h>

typedef __attribute__((ext_vector_type(8))) short bf16x8;
typedef __attribute__((ext_vector_type(4))) float f32x4;

static constexpr int HH = 224, WW = 224;
static constexpr int CIN = 64;
static constexpr int HW = HH * WW;   // 50176

__device__ __forceinline__ ushort f2bf(float f) {
    unsigned u = __builtin_bit_cast(unsigned, f);
    u += 0x7FFFu + ((u >> 16) & 1u);   // round-to-nearest-even
    return (ushort)(u >> 16);
}

// ws layout (ushort units):
//   w1r  [0, 36864)        9*64*64 bf16, [ch][n][c]           (fallback kernel)
//   w2r  [36864, 40960)    64*64 bf16
//   zp   [40960, 41024)    128 B of zeros (halo zero-page)
//   w1x  [41024, 77888)    W1 fragment-contiguous: [(ch*8+s*4+nt)][lane][j]
//   xt   [77888, +8*HW*64) x as bf16, [b][p=y*W+x][c]  (51.4 MB)
__global__ void prep_kernel(const float* __restrict__ W1, const float* __restrict__ W2,
                            ushort* __restrict__ ws, int nfill) {
    const int idx = blockIdx.x * 256 + threadIdx.x;
    if (idx < 36864) {
        const int ch = idx >> 12;
        const int n = (idx >> 6) & 63;
        const int c = idx & 63;
        ws[idx] = f2bf(W1[n * 576 + c * 9 + ch]);
    } else if (idx < 40960) {
        ws[idx] = f2bf(W2[idx - 36864]);
    } else if (idx < 41024) {
        if (idx < nfill) ws[idx] = 0;
    } else if (idx < nfill) {          // 41024..77888: w1x
        const int k = idx - 41024;
        const int j = k & 7;
        const int l15 = (k >> 3) & 15;
        const int quad = (k >> 7) & 3;
        const int nt = (k >> 9) & 3;
        const int s = (k >> 11) & 1;
        const int ch = k >> 12;
        const int n = nt * 16 + l15;
        const int c = s * 32 + quad * 8 + j;
        ws[idx] = f2bf(W1[n * 576 + c * 9 + ch]);
    }
}

#define GLD_LDS16(g, l) __builtin_amdgcn_global_load_lds(                  \
    (const __attribute__((address_space(1))) void*)(g),                    \
    (__attribute__((address_space(3))) void*)(l), 16, 0, 0)

// Transpose+convert x fp32 [b][c][p] -> xt bf16 [b][p][c], DMA-staged:
// global_load_lds gives unbounded outstanding-bytes (no VGPR cost), unlike
// the old reg-staged version whose in-flight bytes were capped by
// VGPR x occupancy (~2.7 TB/s). Per block: 64 ch x 256 px fp32 via 64
// contiguous 1KB DMAs -> LDS [c][257] (pad: transposed read = 2-way
// conflict, free) -> 8 contiguous 1KB stores per wave.
__global__ __launch_bounds__(256)
void xprep_kernel(const float* __restrict__ xin, ushort* __restrict__ xt) {
    __shared__ float xsf[64 * 257];   // 65,792 B -> 2 blocks/CU

    const int b = blockIdx.y;
    const int p0 = blockIdx.x * 256;
    const float* xg = xin + (size_t)b * (CIN * HW);
    ushort* xo = xt + (size_t)b * ((size_t)HW * 64);

    const int tid = threadIdx.x;
    const int wave = tid >> 6;
    const int lane = tid & 63;

    // stage: wave w loads channels w*16..w*16+15; 1KB contiguous per issue
    #pragma unroll
    for (int i = 0; i < 16; ++i) {
        const int c = wave * 16 + i;
        GLD_LDS16(xg + (size_t)c * HW + p0 + lane * 4, &xsf[c * 257]);
    }

    asm volatile("s_waitcnt vmcnt(0)" ::: "memory");
    __syncthreads();

    // transpose-out: wave w owns px chunk [w*64, w*64+64); per store,
    // lane l covers px = +s*8+(l>>3), channels (l&7)*8..+7 -> 1KB contiguous
    const int lpx = lane >> 3;
    const int cg8 = (lane & 7) * 8;
    #pragma unroll
    for (int s = 0; s < 8; ++s) {
        const int px = wave * 64 + s * 8 + lpx;   // within [0,256)
        bf16x8 o;
        #pragma unroll
        for (int j = 0; j < 8; ++j)
            o[j] = (short)f2bf(xsf[(cg8 + j) * 257 + px]);
        *reinterpret_cast<bf16x8*>(xo + (size_t)(p0 + px) * 64 + cg8) = o;
    }
}

// Round-9 verified kernel (UNCHANGED): 4 waves x 64px x 64hid, acc[4][4],
// unroll-2 k-loop, fragment-contiguous W1, float4-store epilogue.
__global__ __launch_bounds__(256, 3)
void mlpconv_fast(const ushort* __restrict__ xt, const ushort* __restrict__ w1x,
                  const float* __restrict__ b1, const ushort* __restrict__ w2r,
                  const float* __restrict__ b2, const ushort* __restrict__ zp,
                  float* __restrict__ out) {
    __shared__ ushort xs[10 * 40 * 64];   // 51,200 B -> 3 blocks/CU

    const int tid = threadIdx.x;
    const int wave = tid >> 6;
    const int lane = tid & 63;
    const int l15 = lane & 15;
    const int quad = lane >> 4;

    const int x0 = blockIdx.x * 32;   // 7
    const int y0 = blockIdx.y * 8;    // 28
    const int b = blockIdx.z;         // 8

    const ushort* xtb = xt + (size_t)b * ((size_t)HW * 64);

    const int lpx = lane >> 3;
    const int laneoff = lpx * 64 + (((lane & 7) ^ lpx) * 8);   // ushort offset

    for (int q = wave; q < 50; q += 4) {     // 10 rows x 5 segments of 8 px
        const int r = q / 5;
        const int i = q - 5 * r;
        const int gy = y0 + r - 1;
        const int gx0 = x0 - 4 + i * 8;
        const ushort* real = xtb + (long)(gy * WW + gx0) * 64 + laneoff;
        const bool ok = ((unsigned)gy < (unsigned)HH) &
                        ((unsigned)(gx0 + lpx) < (unsigned)WW);
        const ushort* src = ok ? real : zp;   // halo lanes read the zero page
        GLD_LDS16(src, &xs[(r * 40 + i * 8) * 64]);
    }

    float b1v[4];
    #pragma unroll
    for (int nt = 0; nt < 4; ++nt) b1v[nt] = b1[nt * 16 + l15];

    f32x4 acc[4][4];   // C layout: col=lane&15 (=n hid), row=quad*4+reg (=m px)
    #pragma unroll
    for (int mt = 0; mt < 4; ++mt)
        #pragma unroll
        for (int nt = 0; nt < 4; ++nt)
            acc[mt][nt] = (f32x4){b1v[nt], b1v[nt], b1v[nt], b1v[nt]};

    asm volatile("s_waitcnt vmcnt(0)" ::: "memory");
    __syncthreads();

    // ---- main loop: 18 k-steps (9 taps x 2 halves of 32 ch), barrier-free.
    #pragma unroll 2
    for (int ks = 0; ks < 18; ++ks) {
        const int ch = ks >> 1;
        const int s = ks & 1;
        const int dy = ch / 3, dx = ch - 3 * (ch / 3);
        const int ko = s * 32 + quad * 8;
        bf16x8 bfr[4];
        #pragma unroll
        for (int nt = 0; nt < 4; ++nt)
            bfr[nt] = *reinterpret_cast<const bf16x8*>(
                w1x + ks * 2048 + nt * 512 + lane * 8);   // contiguous 1KB/wave
        const int kswz = ko ^ (((l15 + dx + 3) & 7) * 8);
        #pragma unroll
        for (int mt = 0; mt < 4; ++mt) {
            const int row = 2 * wave + (mt >> 1) + dy;
            const int col = (mt & 1) * 16 + l15 + dx + 3;
            const bf16x8 afr = *reinterpret_cast<const bf16x8*>(
                &xs[(row * 40 + col) * 64 + kswz]);
            #pragma unroll
            for (int nt = 0; nt < 4; ++nt)
                acc[mt][nt] = __builtin_amdgcn_mfma_f32_16x16x32_bf16(
                    afr, bfr[nt], acc[mt][nt], 0, 0, 0);
        }
    }

    __syncthreads();   // other waves may still read xs; about to overwrite as h-scratch

    // ---- epilogue: ReLU -> bf16 h (per-wave LDS) -> GEMM2 (h as A, W2 as B)
    //      -> +b2 -> float4 stores.
    float b2v[4];
    #pragma unroll
    for (int it = 0; it < 4; ++it) b2v[it] = b2[it * 16 + l15];

    bf16x8 wa2[2][4];   // W2 fragments: lane l15 = cout col, quad*8+j = k (B operand)
    #pragma unroll
    for (int k2 = 0; k2 < 2; ++k2)
        #pragma unroll
        for (int it = 0; it < 4; ++it)
            wa2[k2][it] = *reinterpret_cast<const bf16x8*>(
                w2r + (it * 16 + l15) * 64 + k2 * 32 + quad * 8);

    ushort* myh = &xs[wave * (16 * 72)];
    float* outg = out + (size_t)b * (64 * HH * WW);

    #pragma unroll
    for (int mt = 0; mt < 4; ++mt) {
        #pragma unroll
        for (int ni = 0; ni < 4; ++ni)
            #pragma unroll
            for (int r = 0; r < 4; ++r) {
                float v = acc[mt][ni][r];
                v = v > 0.f ? v : 0.f;
                myh[(quad * 4 + r) * 72 + ni * 16 + l15] = f2bf(v);
            }
        f32x4 acc2[4];   // D2: row=quad*4+reg (=px), col=lane&15 (=cout)
        #pragma unroll
        for (int it = 0; it < 4; ++it)
            acc2[it] = (f32x4){b2v[it], b2v[it], b2v[it], b2v[it]};
        #pragma unroll
        for (int k2 = 0; k2 < 2; ++k2) {
            const bf16x8 hb = *reinterpret_cast<const bf16x8*>(
                &myh[l15 * 72 + k2 * 32 + quad * 8]);   // A: lane=px row, quad*8+j=k
            #pragma unroll
            for (int it = 0; it < 4; ++it)
                acc2[it] = __builtin_amdgcn_mfma_f32_16x16x32_bf16(
                    hb, wa2[k2][it], acc2[it], 0, 0, 0);
        }
        const int gy = y0 + 2 * wave + (mt >> 1);
        const int gxb = x0 + (mt & 1) * 16 + quad * 4;
        #pragma unroll
        for (int it = 0; it < 4; ++it) {
            const int o = it * 16 + l15;
            *reinterpret_cast<f32x4*>(outg + ((size_t)o * HH + gy) * WW + gxb)
                = acc2[it];
        }
    }
}

// Fallback (workspace too small for xt): the verified baseline kernel (old w1r layout).
__global__ __launch_bounds__(256, 3)
void mlpconv_kernel(const float* __restrict__ xin, const ushort* __restrict__ w1r,
                    const float* __restrict__ b1, const ushort* __restrict__ w2r,
                    const float* __restrict__ b2, float* __restrict__ out) {
    __shared__ ushort xs[10 * 40 * 64];

    const int tid = threadIdx.x;
    const int wave = tid >> 6;
    const int lane = tid & 63;
    const int l15 = lane & 15;
    const int quad = lane >> 4;

    const int x0 = blockIdx.x * 32;
    const int y0 = blockIdx.y * 8;
    const int b = blockIdx.z;

    const float* xg = xin + (size_t)b * (CIN * HH * WW);

    for (int e = tid; e < 6400; e += 256) {
        const int i = e % 10;
        const int t = e / 10;
        const int c = t & 63;
        const int r = t >> 6;
        const int gy = y0 + r - 1;
        const int gx4 = x0 - 4 + i * 4;
        float4 v = make_float4(0.f, 0.f, 0.f, 0.f);
        if (((unsigned)gy < (unsigned)HH) && ((unsigned)gx4 <= 220u))
            v = *reinterpret_cast<const float4*>(xg + (c * HH + gy) * WW + gx4);
        const int p0 = r * 40 + i * 4;
        xs[(p0 + 0) * 64 + (c ^ (((p0 + 0) & 7) * 8))] = f2bf(v.x);
        xs[(p0 + 1) * 64 + (c ^ (((p0 + 1) & 7) * 8))] = f2bf(v.y);
        xs[(p0 + 2) * 64 + (c ^ (((p0 + 2) & 7) * 8))] = f2bf(v.z);
        xs[(p0 + 3) * 64 + (c ^ (((p0 + 3) & 7) * 8))] = f2bf(v.w);
    }

    float b1v[4];
    #pragma unroll
    for (int nt = 0; nt < 4; ++nt) b1v[nt] = b1[nt * 16 + l15];

    f32x4 acc[4][4];
    #pragma unroll
    for (int mt = 0; mt < 4; ++mt)
        #pragma unroll
        for (int nt = 0; nt < 4; ++nt)
            acc[mt][nt] = (f32x4){b1v[nt], b1v[nt], b1v[nt], b1v[nt]};

    __syncthreads();

    #pragma unroll 2
    for (int ks = 0; ks < 18; ++ks) {
        const int ch = ks >> 1;
        const int s = ks & 1;
        const int dy = ch / 3, dx = ch - 3 * (ch / 3);
        const int ko = s * 32 + quad * 8;
        bf16x8 bfr[4];
        #pragma unroll
        for (int nt = 0; nt < 4; ++nt)
            bfr[nt] = *reinterpret_cast<const bf16x8*>(
                w1r + ch * 4096 + (nt * 16 + l15) * 64 + ko);
        const int kswz = ko ^ (((l15 + dx + 3) & 7) * 8);
        #pragma unroll
        for (int mt = 0; mt < 4; ++mt) {
            const int row = 2 * wave + (mt >> 1) + dy;
            const int col = (mt & 1) * 16 + l15 + dx + 3;
            const bf16x8 afr = *reinterpret_cast<const bf16x8*>(
                &xs[(row * 40 + col) * 64 + kswz]);
            #pragma unroll
            for (int nt = 0; nt < 4; ++nt)
                acc[mt][nt] = __builtin_amdgcn_mfma_f32_16x16x32_bf16(
                    afr, bfr[nt], acc[mt][nt], 0, 0, 0);
        }
    }

    __syncthreads();

    float4 b2q[4];
    #pragma unroll
    for (int it = 0; it < 4; ++it)
        b2q[it] = *reinterpret_cast<const float4*>(b2 + it * 16 + quad * 4);

    bf16x8 wa2[2][4];
    #pragma unroll
    for (int k2 = 0; k2 < 2; ++k2)
        #pragma unroll
        for (int it = 0; it < 4; ++it)
            wa2[k2][it] = *reinterpret_cast<const bf16x8*>(
                w2r + (it * 16 + l15) * 64 + k2 * 32 + quad * 8);

    ushort* myh = &xs[wave * (16 * 72)];
    float* outg = out + (size_t)b * (64 * HH * WW);

    #pragma unroll
    for (int mt = 0; mt < 4; ++mt) {
        #pragma unroll
        for (int ni = 0; ni < 4; ++ni)
            #pragma unroll
            for (int r = 0; r < 4; ++r) {
                float v = acc[mt][ni][r];
                v = v > 0.f ? v : 0.f;
                myh[(quad * 4 + r) * 72 + ni * 16 + l15] = f2bf(v);
            }
        f32x4 acc2[4];
        #pragma unroll
        for (int it = 0; it < 4; ++it)
            acc2[it] = (f32x4){b2q[it].x, b2q[it].y, b2q[it].z, b2q[it].w};
        #pragma unroll
        for (int k2 = 0; k2 < 2; ++k2) {
            const bf16x8 hb = *reinterpret_cast<const bf16x8*>(
                &myh[l15 * 72 + k2 * 32 + quad * 8]);
            #pragma unroll
            for (int it = 0; it < 4; ++it)
                acc2[it] = __builtin_amdgcn_mfma_f32_16x16x32_bf16(
                    wa2[k2][it], hb, acc2[it], 0, 0, 0);
        }
        const int gy = y0 + 2 * wave + (mt >> 1);
        const int gx = x0 + (mt & 1) * 16 + l15;
        #pragma unroll
        for (int it = 0; it < 4; ++it)
            #pragma unroll
            for (int r = 0; r < 4; ++r) {
                const int o = it * 16 + quad * 4 + r;
                outg[(o * HH + gy) * WW + gx] = acc2[it][r];
            }
    }
}

extern "C" void kernel_launch(void* const* d_in, const int* in_sizes, int n_in,
                              void* d_out, int out_size, void* d_ws, size_t ws_size,
                              hipStream_t stream) {
    const float* x  = (const float*)d_in[0];
    const float* W1 = (const float*)d_in[1];
    const float* b1 = (const float*)d_in[2];
    const float* W2 = (const float*)d_in[3];
    const float* b2 = (const float*)d_in[4];
    float* out = (float*)d_out;

    ushort* ws  = (ushort*)d_ws;
    ushort* w1r = ws;                 // 36,864 ushorts (fallback layout)
    ushort* w2r = ws + 36864;         // 4,096 ushorts
    ushort* zp  = ws + 40960;         // 64 ushorts (zero page)
    ushort* w1x = ws + 41024;         // 36,864 ushorts (fragment-contiguous)
    ushort* xt  = ws + 77888;         // 8*HW*64 ushorts = 51.4 MB

    const size_t need = (size_t)77888 * 2 + (size_t)8 * HW * 64 * 2;
    const bool fast = ws_size >= need;

    prep_kernel<<<305, 256, 0, stream>>>(W1, W2, ws, fast ? 77888 : 40960);
    dim3 grid(WW / 32, HH / 8, 8);    // (7, 28, 8)
    if (fast) {
        xprep_kernel<<<dim3(HW / 256, 8), 256, 0, stream>>>(x, xt);   // (196, 8)
        mlpconv_fast<<<grid, dim3(256), 0, stream>>>(xt, w1x, b1, w2r, b2, zp, out);
    } else {
        mlpconv_kernel<<<grid, dim3(256), 0, stream>>>(x, w1r, b1, w2r, b2, out);
    }
}